// Round 4
// baseline (81.174 us; speedup 1.0000x reference)
//
#include <hip/hip_runtime.h>

typedef __attribute__((ext_vector_type(4))) float v4f;
typedef __attribute__((ext_vector_type(8))) short short8;
typedef unsigned short u16;
typedef __attribute__((ext_vector_type(4))) unsigned short u16x4;
typedef __attribute__((ext_vector_type(8))) unsigned short u16x8;

#define CDIM 256
#define NB 8
#define NN 4096
#define MM 4096

static __device__ __forceinline__ u16 f2bf(float f) {
  unsigned u = __float_as_uint(f);
  u = (u + 0x7fffu + ((u >> 16) & 1u)) >> 16;  // RNE
  return (u16)u;
}
static __device__ __forceinline__ float bf2f(u16 h) {
  return __uint_as_float(((unsigned)h) << 16);
}

// ---------------- K1: kv partials = v^T @ (k/||k||), split-K, output [d][c] ----------------
// Phase 0 fuses the row-norm pass: each wave reads whole k-rows (16B/lane), shfl-reduces,
// stores inv-norms to LDS. Staging then re-reads k from the L2-warm tile.
__global__ __launch_bounds__(512, 2) void kv_kernel(const float* __restrict__ key,
                                                    const float* __restrict__ value,
                                                    u16* __restrict__ partial, int KC) {
  __shared__ __align__(16) u16 knT[256 * 64];  // [c][m] bf16, XOR-swizzled
  __shared__ __align__(16) u16 vT[256 * 64];   // [d][m] bf16, XOR-swizzled
  __shared__ float skl[2048];                  // inv-norms for this split's rows
  int t = threadIdx.x;
  int b = blockIdx.y, s = blockIdx.x;
  int w = t >> 6, lane = t & 63, lo = lane & 15, hi = lane >> 4;
  int cstage = t & 255, wq = t >> 8;

  // phase 0: inv-norms of this split's KC rows (row-per-wave, coalesced v4f)
  int rpw = KC >> 3;  // rows per wave (8 waves)
  const float* kbase = key + (size_t)(b * MM + s * KC) * CDIM;
  for (int i = 0; i < rpw; ++i) {
    int m = w * rpw + i;
    const v4f x = *(const v4f*)(kbase + (size_t)m * CDIM + lane * 4);
    float ss = x[0]*x[0] + x[1]*x[1] + x[2]*x[2] + x[3]*x[3];
    #pragma unroll
    for (int mm = 1; mm < 64; mm <<= 1) ss += __shfl_xor(ss, mm);
    if (lane == 0) skl[m] = 1.0f / fmaxf(sqrtf(ss), 1e-12f);
  }
  __syncthreads();

  v4f acc[2][16];
  #pragma unroll
  for (int i = 0; i < 2; i++)
    #pragma unroll
    for (int d = 0; d < 16; d++) acc[i][d] = (v4f){0.f, 0.f, 0.f, 0.f};

  int nsc = KC >> 6;
  for (int sc = 0; sc < nsc; ++sc) {
    int mbase = s * KC + sc * 64;
    // stage 64 m-rows: transpose + normalize(k) + bf16 (k hits L2 from phase 0)
    #pragma unroll
    for (int it = 0; it < 8; ++it) {
      int ml0 = it * 8 + wq * 4;
      int gr = b * MM + mbase + ml0;
      int lr = sc * 64 + ml0;
      size_t grow = (size_t)gr * CDIM + cstage;
      float k0 = key[grow], k1 = key[grow + CDIM], k2 = key[grow + 2 * CDIM], k3 = key[grow + 3 * CDIM];
      float s0 = skl[lr], s1 = skl[lr + 1], s2 = skl[lr + 2], s3 = skl[lr + 3];
      u16x4 kn = { f2bf(k0 * s0), f2bf(k1 * s1), f2bf(k2 * s2), f2bf(k3 * s3) };
      int idx = (cstage * 64 + ml0) ^ ((cstage & 7) << 3);
      *(u16x4*)&knT[idx] = kn;
      float v0 = value[grow], v1 = value[grow + CDIM], v2 = value[grow + 2 * CDIM], v3 = value[grow + 3 * CDIM];
      u16x4 vn = { f2bf(v0), f2bf(v1), f2bf(v2), f2bf(v3) };
      *(u16x4*)&vT[idx] = vn;
    }
    __syncthreads();
    // MFMA (operands swapped => output rows=d, cols=c):
    // wave w owns c-tiles {2w, 2w+1} x all 16 d-tiles
    #pragma unroll
    for (int kk = 0; kk < 64; kk += 32) {
      int acol = kk + hi * 8;
      int r0 = w * 32 + lo, r1 = w * 32 + 16 + lo;
      short8 a0 = *(const short8*)&knT[(r0 * 64 + acol) ^ ((r0 & 7) << 3)];
      short8 a1 = *(const short8*)&knT[(r1 * 64 + acol) ^ ((r1 & 7) << 3)];
      #pragma unroll
      for (int dt = 0; dt < 16; ++dt) {
        int drow = dt * 16 + lo;
        short8 bb = *(const short8*)&vT[(drow * 64 + acol) ^ ((drow & 7) << 3)];
        acc[0][dt] = __builtin_amdgcn_mfma_f32_16x16x32_bf16(bb, a0, acc[0][dt], 0, 0, 0);
        acc[1][dt] = __builtin_amdgcn_mfma_f32_16x16x32_bf16(bb, a1, acc[1][dt], 0, 0, 0);
      }
    }
    __syncthreads();
  }
  // epilogue: bf16 partial [s][b][256 d][256 c]
  size_t base = ((size_t)(s * NB + b)) << 16;
  #pragma unroll
  for (int i = 0; i < 2; i++) {
    int cc = w * 32 + i * 16 + lo;
    #pragma unroll
    for (int dt = 0; dt < 16; ++dt) {
      int dd = dt * 16 + hi * 4;
      #pragma unroll
      for (int r = 0; r < 4; r++)
        partial[base + (size_t)(dd + r) * 256 + cc] = f2bf(acc[i][dt][r]);
    }
  }
}

// ---------------- K2: elementwise reduce partials, scale 1/N, write kvT[d][c] bf16 ----------------
__global__ __launch_bounds__(256) void red_kernel(const u16* __restrict__ partial,
                                                  u16* __restrict__ kvT, int splits) {
  int j = blockIdx.x * 256 + threadIdx.x;   // 0..65535
  int b = j >> 13;
  int e0 = (j & 8191) * 8;
  size_t off = ((size_t)b << 16) + e0;
  const float inv = 1.0f / 4096.0f;
  float sum[8] = {0.f, 0.f, 0.f, 0.f, 0.f, 0.f, 0.f, 0.f};
  for (int s = 0; s < splits; ++s) {
    u16x8 p = *(const u16x8*)&partial[(((size_t)s * NB) << 16) + off];
    #pragma unroll
    for (int x = 0; x < 8; ++x) sum[x] += bf2f(p[x]);
  }
  u16x8 o;
  #pragma unroll
  for (int x = 0; x < 8; ++x) o[x] = f2bf(sum[x] * inv);
  *(u16x8*)&kvT[off] = o;
}

// ---------------- K3: out = normalize(q) @ kv, kv in registers, 1 tile/block ----------------
// 2048 blocks x 512 threads (8 waves). Wave w owns d-tiles {2w,2w+1}. One barrier total.
__global__ __launch_bounds__(512) void ctx_kernel(const float* __restrict__ query,
                                                  const u16* __restrict__ kvT,
                                                  float* __restrict__ out) {
  __shared__ __align__(16) u16 qn[16 * 256];  // 8 KB q-hat tile, XOR-swizzled
  int t = threadIdx.x;
  int b = blockIdx.y;
  int n0 = blockIdx.x * 16;
  int w = t >> 6, lane = t & 63, lo = lane & 15, hi = lane >> 4;

  // 1) issue q loads first — HBM latency hides under the kv prologue below
  int row = t >> 5, l32 = t & 31;  // 16 rows x 32 lanes x 8 floats
  const float* qr = query + (size_t)(b * NN + n0 + row) * CDIM + l32 * 8;
  v4f x0 = *(const v4f*)qr;
  v4f x1 = *(const v4f*)(qr + 4);

  // 2) kv B-fragments from L2 (kvT is 2 MB total, L2-resident)
  const u16* kvb = kvT + ((size_t)b << 16);
  short8 Bf[2][8];
  #pragma unroll
  for (int i = 0; i < 2; i++) {
    int dr = (2 * w + i) * 16 + lo;
    #pragma unroll
    for (int kc = 0; kc < 8; kc++)
      Bf[i][kc] = *(const short8*)&kvb[(size_t)dr * 256 + kc * 32 + 8 * hi];
  }

  // 3) normalize q row (32-lane reduce), bf16, stage to LDS
  float ss = x0[0]*x0[0] + x0[1]*x0[1] + x0[2]*x0[2] + x0[3]*x0[3]
           + x1[0]*x1[0] + x1[1]*x1[1] + x1[2]*x1[2] + x1[3]*x1[3];
  #pragma unroll
  for (int m = 1; m < 32; m <<= 1) ss += __shfl_xor(ss, m);
  float sc = 1.0f / fmaxf(sqrtf(ss), 1e-12f);
  u16x8 qb;
  qb[0] = f2bf(x0[0] * sc); qb[1] = f2bf(x0[1] * sc);
  qb[2] = f2bf(x0[2] * sc); qb[3] = f2bf(x0[3] * sc);
  qb[4] = f2bf(x1[0] * sc); qb[5] = f2bf(x1[1] * sc);
  qb[6] = f2bf(x1[2] * sc); qb[7] = f2bf(x1[3] * sc);
  *(u16x8*)&qn[(row * 256 + l32 * 8) ^ ((row & 7) << 3)] = qb;
  __syncthreads();

  // 4) A-frags + MFMA + store
  short8 Af[8];
  #pragma unroll
  for (int kc = 0; kc < 8; kc++)
    Af[kc] = *(const short8*)&qn[(lo * 256 + kc * 32 + 8 * hi) ^ ((lo & 7) << 3)];
  v4f acc0 = (v4f){0.f, 0.f, 0.f, 0.f};
  v4f acc1 = (v4f){0.f, 0.f, 0.f, 0.f};
  #pragma unroll
  for (int kc = 0; kc < 8; kc++) {
    acc0 = __builtin_amdgcn_mfma_f32_16x16x32_bf16(Af[kc], Bf[0][kc], acc0, 0, 0, 0);
    acc1 = __builtin_amdgcn_mfma_f32_16x16x32_bf16(Af[kc], Bf[1][kc], acc1, 0, 0, 0);
  }
  #pragma unroll
  for (int r = 0; r < 4; r++) {
    size_t ro = (size_t)(b * NN + n0 + 4 * hi + r) * CDIM;
    out[ro + (2 * w) * 16 + lo] = acc0[r];
    out[ro + (2 * w + 1) * 16 + lo] = acc1[r];
  }
}

extern "C" void kernel_launch(void* const* d_in, const int* in_sizes, int n_in,
                              void* d_out, int out_size, void* d_ws, size_t ws_size,
                              hipStream_t stream) {
  const float* q = (const float*)d_in[0];
  const float* k = (const float*)d_in[1];
  const float* v = (const float*)d_in[2];
  float* out = (float*)d_out;

  // ws layout: [partial: splits*8*256*256 bf16][kvT: 8*256*256 bf16]
  int splits = 32;
  while (splits > 2) {
    size_t need = ((size_t)splits + 1ull) * 1048576ull;
    if (need <= ws_size) break;
    splits >>= 1;
  }
  u16* partial = (u16*)d_ws;
  u16* kvT = (u16*)((char*)d_ws + (size_t)splits * 1048576ull);

  kv_kernel<<<dim3(splits, NB), dim3(512), 0, stream>>>(k, v, partial, MM / splits);
  red_kernel<<<dim3(256), dim3(256), 0, stream>>>(partial, kvT, splits);
  ctx_kernel<<<dim3(256, NB), dim3(512), 0, stream>>>(q, kvT, out);
}

// Round 5
// 63.999 us; speedup vs baseline: 1.2684x; 1.2684x over previous
//
#include <hip/hip_runtime.h>

typedef __attribute__((ext_vector_type(4))) float v4f;
typedef __attribute__((ext_vector_type(8))) short short8;
typedef unsigned short u16;
typedef __attribute__((ext_vector_type(4))) unsigned short u16x4;
typedef __attribute__((ext_vector_type(8))) unsigned short u16x8;

#define CDIM 256
#define NB 8
#define NN 4096
#define MM 4096

static __device__ __forceinline__ u16 f2bf(float f) {
  unsigned u = __float_as_uint(f);
  u = (u + 0x7fffu + ((u >> 16) & 1u)) >> 16;  // RNE
  return (u16)u;
}
static __device__ __forceinline__ float bf2f(u16 h) {
  return __uint_as_float(((unsigned)h) << 16);
}

// ---------------- K0: inv-norms of key rows ----------------
__global__ __launch_bounds__(256) void knorm_kernel(const float* __restrict__ key,
                                                    float* __restrict__ sk) {
  int t = threadIdx.x;
  int lane = t & 63;
  int r = blockIdx.x * 4 + (t >> 6);
  const v4f x = *(const v4f*)(key + (size_t)r * CDIM + lane * 4);
  float ss = x[0]*x[0] + x[1]*x[1] + x[2]*x[2] + x[3]*x[3];
  #pragma unroll
  for (int m = 1; m < 64; m <<= 1) ss += __shfl_xor(ss, m);
  if (lane == 0) sk[r] = 1.0f / fmaxf(sqrtf(ss), 1e-12f);
}

// ---------------- K1: kv partials = v^T @ (k*s), split-K, output [d][c] ----------------
__global__ __launch_bounds__(512, 2) void kv_kernel(const float* __restrict__ key,
                                                    const float* __restrict__ value,
                                                    const float* __restrict__ sk,
                                                    u16* __restrict__ partial, int KC) {
  __shared__ __align__(16) u16 knT[256 * 64];  // [c][m] bf16, XOR-swizzled
  __shared__ __align__(16) u16 vT[256 * 64];   // [d][m] bf16, XOR-swizzled
  int t = threadIdx.x;
  int b = blockIdx.y, s = blockIdx.x;
  int w = t >> 6, lane = t & 63, lo = lane & 15, hi = lane >> 4;
  int cstage = t & 255, wq = t >> 8;

  v4f acc[2][16];
  #pragma unroll
  for (int i = 0; i < 2; i++)
    #pragma unroll
    for (int d = 0; d < 16; d++) acc[i][d] = (v4f){0.f, 0.f, 0.f, 0.f};

  int nsc = KC >> 6;
  for (int sc = 0; sc < nsc; ++sc) {
    int mbase = s * KC + sc * 64;
    // stage 64 m-rows: transpose + normalize(k) + bf16
    #pragma unroll
    for (int it = 0; it < 8; ++it) {
      int ml0 = it * 8 + wq * 4;
      int gr = b * MM + mbase + ml0;
      size_t grow = (size_t)gr * CDIM + cstage;
      float k0 = key[grow], k1 = key[grow + CDIM], k2 = key[grow + 2 * CDIM], k3 = key[grow + 3 * CDIM];
      float s0 = sk[gr], s1 = sk[gr + 1], s2 = sk[gr + 2], s3 = sk[gr + 3];
      u16x4 kn = { f2bf(k0 * s0), f2bf(k1 * s1), f2bf(k2 * s2), f2bf(k3 * s3) };
      int idx = (cstage * 64 + ml0) ^ ((cstage & 7) << 3);
      *(u16x4*)&knT[idx] = kn;
      float v0 = value[grow], v1 = value[grow + CDIM], v2 = value[grow + 2 * CDIM], v3 = value[grow + 3 * CDIM];
      u16x4 vn = { f2bf(v0), f2bf(v1), f2bf(v2), f2bf(v3) };
      *(u16x4*)&vT[idx] = vn;
    }
    __syncthreads();
    // MFMA (operands swapped => output rows=d, cols=c):
    // wave w owns c-tiles {2w, 2w+1} x all 16 d-tiles
    #pragma unroll
    for (int kk = 0; kk < 64; kk += 32) {
      int acol = kk + hi * 8;
      int r0 = w * 32 + lo, r1 = w * 32 + 16 + lo;
      short8 a0 = *(const short8*)&knT[(r0 * 64 + acol) ^ ((r0 & 7) << 3)];
      short8 a1 = *(const short8*)&knT[(r1 * 64 + acol) ^ ((r1 & 7) << 3)];
      #pragma unroll
      for (int dt = 0; dt < 16; ++dt) {
        int drow = dt * 16 + lo;
        short8 bb = *(const short8*)&vT[(drow * 64 + acol) ^ ((drow & 7) << 3)];
        acc[0][dt] = __builtin_amdgcn_mfma_f32_16x16x32_bf16(bb, a0, acc[0][dt], 0, 0, 0);
        acc[1][dt] = __builtin_amdgcn_mfma_f32_16x16x32_bf16(bb, a1, acc[1][dt], 0, 0, 0);
      }
    }
    __syncthreads();
  }
  // epilogue: bf16 partial [s][b][256 d][256 c]
  size_t base = ((size_t)(s * NB + b)) << 16;
  #pragma unroll
  for (int i = 0; i < 2; i++) {
    int cc = w * 32 + i * 16 + lo;
    #pragma unroll
    for (int dt = 0; dt < 16; ++dt) {
      int dd = dt * 16 + hi * 4;
      #pragma unroll
      for (int r = 0; r < 4; r++)
        partial[base + (size_t)(dd + r) * 256 + cc] = f2bf(acc[i][dt][r]);
    }
  }
}

// ---------------- K2: elementwise reduce partials, scale 1/N, write kvT[d][c] bf16 ----------------
__global__ __launch_bounds__(256) void red_kernel(const u16* __restrict__ partial,
                                                  u16* __restrict__ kvT, int splits) {
  int j = blockIdx.x * 256 + threadIdx.x;   // 0..65535
  int b = j >> 13;
  int e0 = (j & 8191) * 8;
  size_t off = ((size_t)b << 16) + e0;
  const float inv = 1.0f / 4096.0f;
  float sum[8] = {0.f, 0.f, 0.f, 0.f, 0.f, 0.f, 0.f, 0.f};
  for (int s = 0; s < splits; ++s) {
    u16x8 p = *(const u16x8*)&partial[(((size_t)s * NB) << 16) + off];
    #pragma unroll
    for (int x = 0; x < 8; ++x) sum[x] += bf2f(p[x]);
  }
  u16x8 o;
  #pragma unroll
  for (int x = 0; x < 8; ++x) o[x] = f2bf(sum[x] * inv);
  *(u16x8*)&kvT[off] = o;
}

// ---------------- K3: out = normalize(q) @ kv ----------------
// 512 blocks x 512 threads (8 waves). Wave w owns d-tiles {2w,2w+1}; kv frags in regs.
// 4 n-tiles (16 rows) per block, double-buffered LDS + register prefetch, 1 barrier/tile.
__global__ __launch_bounds__(512) void ctx_kernel(const float* __restrict__ query,
                                                  const u16* __restrict__ kvT,
                                                  float* __restrict__ out) {
  __shared__ __align__(16) u16 qn[2][16 * 256];  // 2 x 8 KB q-hat tiles, XOR-swizzled
  int t = threadIdx.x;
  int b = blockIdx.y;
  int tile0 = blockIdx.x * 4;
  int w = t >> 6, lane = t & 63, lo = lane & 15, hi = lane >> 4;
  int row = t >> 5, l32 = t & 31;  // staging role: 16 rows x 32 segs x 8 floats
  const float* qbase = query + (size_t)b * NN * CDIM + (size_t)row * CDIM + l32 * 8;

  // 1) issue tile-0 q loads first (HBM latency hides under the kv prologue)
  const float* qr0 = qbase + (size_t)(tile0 * 16) * CDIM;
  v4f x0 = *(const v4f*)qr0;
  v4f x1 = *(const v4f*)(qr0 + 4);

  // 2) this wave's kv B-fragments (L2-resident, loaded once per block)
  const u16* kvb = kvT + ((size_t)b << 16);
  short8 Bf[2][8];
  #pragma unroll
  for (int i = 0; i < 2; i++) {
    int dr = (2 * w + i) * 16 + lo;
    #pragma unroll
    for (int kc = 0; kc < 8; kc++)
      Bf[i][kc] = *(const short8*)&kvb[(size_t)dr * 256 + kc * 32 + 8 * hi];
  }

  // 3) norm tile 0, stage to LDS[0]
  {
    float ss = x0[0]*x0[0] + x0[1]*x0[1] + x0[2]*x0[2] + x0[3]*x0[3]
             + x1[0]*x1[0] + x1[1]*x1[1] + x1[2]*x1[2] + x1[3]*x1[3];
    #pragma unroll
    for (int m = 1; m < 32; m <<= 1) ss += __shfl_xor(ss, m);
    float sc = 1.0f / fmaxf(sqrtf(ss), 1e-12f);
    u16x8 qb;
    qb[0] = f2bf(x0[0] * sc); qb[1] = f2bf(x0[1] * sc);
    qb[2] = f2bf(x0[2] * sc); qb[3] = f2bf(x0[3] * sc);
    qb[4] = f2bf(x1[0] * sc); qb[5] = f2bf(x1[1] * sc);
    qb[6] = f2bf(x1[2] * sc); qb[7] = f2bf(x1[3] * sc);
    *(u16x8*)&qn[0][(row * 256 + l32 * 8) ^ ((row & 7) << 3)] = qb;
  }

  int cur = 0;
  #pragma unroll
  for (int nt = 0; nt < 4; ++nt) {
    // prefetch next tile's q into registers (flies during MFMA+store below)
    v4f p0, p1;
    if (nt < 3) {
      const float* qr = qbase + (size_t)((tile0 + nt + 1) * 16) * CDIM;
      p0 = *(const v4f*)qr;
      p1 = *(const v4f*)(qr + 4);
    }
    __syncthreads();  // LDS[cur] writes visible to all waves
    // A-frags + MFMA + store for tile nt
    short8 Af[8];
    #pragma unroll
    for (int kc = 0; kc < 8; kc++)
      Af[kc] = *(const short8*)&qn[cur][(lo * 256 + kc * 32 + 8 * hi) ^ ((lo & 7) << 3)];
    v4f acc0 = (v4f){0.f, 0.f, 0.f, 0.f};
    v4f acc1 = (v4f){0.f, 0.f, 0.f, 0.f};
    #pragma unroll
    for (int kc = 0; kc < 8; kc++) {
      acc0 = __builtin_amdgcn_mfma_f32_16x16x32_bf16(Af[kc], Bf[0][kc], acc0, 0, 0, 0);
      acc1 = __builtin_amdgcn_mfma_f32_16x16x32_bf16(Af[kc], Bf[1][kc], acc1, 0, 0, 0);
    }
    int n0 = (tile0 + nt) * 16;
    #pragma unroll
    for (int r = 0; r < 4; r++) {
      size_t ro = (size_t)(b * NN + n0 + 4 * hi + r) * CDIM;
      out[ro + (2 * w) * 16 + lo] = acc0[r];
      out[ro + (2 * w + 1) * 16 + lo] = acc1[r];
    }
    // norm prefetched tile, stage into other buffer (readers of LDS[cur] are done:
    // each wave reads before writing; next barrier orders writes vs next reads)
    if (nt < 3) {
      float ss = p0[0]*p0[0] + p0[1]*p0[1] + p0[2]*p0[2] + p0[3]*p0[3]
               + p1[0]*p1[0] + p1[1]*p1[1] + p1[2]*p1[2] + p1[3]*p1[3];
      #pragma unroll
      for (int m = 1; m < 32; m <<= 1) ss += __shfl_xor(ss, m);
      float sc = 1.0f / fmaxf(sqrtf(ss), 1e-12f);
      u16x8 qb;
      qb[0] = f2bf(p0[0] * sc); qb[1] = f2bf(p0[1] * sc);
      qb[2] = f2bf(p0[2] * sc); qb[3] = f2bf(p0[3] * sc);
      qb[4] = f2bf(p1[0] * sc); qb[5] = f2bf(p1[1] * sc);
      qb[6] = f2bf(p1[2] * sc); qb[7] = f2bf(p1[3] * sc);
      *(u16x8*)&qn[cur ^ 1][(row * 256 + l32 * 8) ^ ((row & 7) << 3)] = qb;
      cur ^= 1;
    }
  }
}

extern "C" void kernel_launch(void* const* d_in, const int* in_sizes, int n_in,
                              void* d_out, int out_size, void* d_ws, size_t ws_size,
                              hipStream_t stream) {
  const float* q = (const float*)d_in[0];
  const float* k = (const float*)d_in[1];
  const float* v = (const float*)d_in[2];
  float* out = (float*)d_out;

  // ws layout: [s_k: 32768 f32][partial: splits*8*256*256 bf16][kvT: 8*256*256 bf16]
  int splits = 32;
  while (splits > 2) {
    size_t need = 131072ull + ((size_t)splits + 1ull) * 1048576ull;
    if (need <= ws_size) break;
    splits >>= 1;
  }
  float* s_k = (float*)d_ws;
  u16* partial = (u16*)((char*)d_ws + 131072);
  u16* kvT = (u16*)((char*)d_ws + 131072 + (size_t)splits * 1048576ull);

  knorm_kernel<<<dim3(8192), dim3(256), 0, stream>>>(k, s_k);
  kv_kernel<<<dim3(splits, NB), dim3(512), 0, stream>>>(k, v, s_k, partial, MM / splits);
  red_kernel<<<dim3(256), dim3(256), 0, stream>>>(partial, kvT, splits);
  ctx_kernel<<<dim3(64, NB), dim3(512), 0, stream>>>(q, kvT, out);
}

// Round 8
// 56.827 us; speedup vs baseline: 1.4284x; 1.1262x over previous
//
#include <hip/hip_runtime.h>

typedef __attribute__((ext_vector_type(4))) float v4f;
typedef __attribute__((ext_vector_type(8))) short short8;
typedef unsigned short u16;
typedef unsigned int u32;
typedef __attribute__((ext_vector_type(2))) unsigned int u32x2;
typedef __attribute__((ext_vector_type(4))) unsigned short u16x4;
typedef __attribute__((ext_vector_type(8))) unsigned short u16x8;

#define CDIM 256
#define NB 8
#define NN 4096
#define MM 4096

static __device__ __forceinline__ u16 f2bf(float f) {
  unsigned u = __float_as_uint(f);
  u = (u + 0x7fffu + ((u >> 16) & 1u)) >> 16;  // RNE
  return (u16)u;
}
static __device__ __forceinline__ float bf2f(u16 h) {
  return __uint_as_float(((unsigned)h) << 16);
}
static __device__ __forceinline__ u32 pack2(float a, float b) {
  return (u32)f2bf(a) | ((u32)f2bf(b) << 16);
}

// 4x4 bf16 transpose among lanes {l, l^16, l^32, l^48}. Lane (hi,lo) holds
// row m0+hi as A=(e0,e1), B=(e2,e3); returns column c0+hi as (rows m0..m0+3).
static __device__ __forceinline__ u32x2 xpose4(u32 A, u32 B, int hi) {
  u32 tA = (u32)__shfl_xor((int)A, 32);
  u32 tB = (u32)__shfl_xor((int)B, 32);
  u32 U = (hi < 2) ? A : tB;   // block transpose (swap off-diagonal 2x2 blocks)
  u32 V = (hi < 2) ? tA : B;
  u32 tU = (u32)__shfl_xor((int)U, 16);
  u32 tV = (u32)__shfl_xor((int)V, 16);
  u32 Up, Vp;
  if ((hi & 1) == 0) {
    Up = (U & 0xffffu) | (tU << 16);
    Vp = (V & 0xffffu) | (tV << 16);
  } else {
    Up = (tU >> 16) | (U & 0xffff0000u);
    Vp = (tV >> 16) | (V & 0xffff0000u);
  }
  return (u32x2){Up, Vp};  // rows m0,m0+1 | m0+2,m0+3 of column c0+hi
}

// ---------------- K1: kv partials = v^T @ (k/||k||), split-K, output [d][c] ----------------
// Vectorized v4f row staging, fused row-norm (wave shfl-reduce), in-register
// 4x4 transpose to the PROVEN [c][m] swizzled LDS layout, dbuf + T14 overlap.
__global__ __launch_bounds__(512) void kv_kernel(const float* __restrict__ key,
                                                 const float* __restrict__ value,
                                                 u16* __restrict__ partial, int KC) {
  __shared__ __align__(16) u16 knT[2][256 * 64];  // [c][m] bf16, XOR-swizzled
  __shared__ __align__(16) u16 vT[2][256 * 64];
  int t = threadIdx.x;
  int b = blockIdx.y, s = blockIdx.x;
  int w = t >> 6, lane = t & 63, lo = lane & 15, hi = lane >> 4;

  const float* kbase = key + ((size_t)b * MM + (size_t)s * KC) * CDIM;
  const float* vbase = value + ((size_t)b * MM + (size_t)s * KC) * CDIM;

  v4f acc[2][16];
  #pragma unroll
  for (int i = 0; i < 2; i++)
    #pragma unroll
    for (int d = 0; d < 16; d++) acc[i][d] = (v4f){0.f, 0.f, 0.f, 0.f};

  v4f kq[4], vq[4];  // one iter's rows: 4 quarters of row m0+hi

  auto LOADS = [&](int sc, int it) {
    int row = sc * 64 + w * 8 + it * 4 + hi;
    const float* kr = kbase + (size_t)row * CDIM + lo * 4;
    const float* vr = vbase + (size_t)row * CDIM + lo * 4;
    #pragma unroll
    for (int qt = 0; qt < 4; ++qt) {
      kq[qt] = *(const v4f*)(kr + qt * 64);
      vq[qt] = *(const v4f*)(vr + qt * 64);
    }
  };
  auto STORE = [&](int bufi, int it) {
    int m0 = w * 8 + it * 4;
    // row norm of k (full row resident across the 16 lanes sharing hi)
    float ss = 0.f;
    #pragma unroll
    for (int qt = 0; qt < 4; ++qt)
      ss += kq[qt][0]*kq[qt][0] + kq[qt][1]*kq[qt][1] + kq[qt][2]*kq[qt][2] + kq[qt][3]*kq[qt][3];
    #pragma unroll
    for (int m = 1; m < 16; m <<= 1) ss += __shfl_xor(ss, m);
    float sc_ = 1.0f / fmaxf(sqrtf(ss), 1e-12f);
    #pragma unroll
    for (int qt = 0; qt < 4; ++qt) {
      int c = qt * 64 + lo * 4 + hi;  // column this lane owns after transpose
      int idx = (c * 64 + m0) ^ ((c & 7) << 3);
      u32x2 ko = xpose4(pack2(kq[qt][0] * sc_, kq[qt][1] * sc_),
                        pack2(kq[qt][2] * sc_, kq[qt][3] * sc_), hi);
      *(u32x2*)&knT[bufi][idx] = ko;
      u32x2 vo = xpose4(pack2(vq[qt][0], vq[qt][1]),
                        pack2(vq[qt][2], vq[qt][3]), hi);
      *(u32x2*)&vT[bufi][idx] = vo;
    }
  };
  auto MF = [&](const u16* KB, const u16* VB) {
    #pragma unroll
    for (int kk = 0; kk < 64; kk += 32) {
      int acol = kk + hi * 8;
      int r0 = w * 32 + lo, r1 = w * 32 + 16 + lo;
      short8 a0 = *(const short8*)&KB[(r0 * 64 + acol) ^ ((r0 & 7) << 3)];
      short8 a1 = *(const short8*)&KB[(r1 * 64 + acol) ^ ((r1 & 7) << 3)];
      #pragma unroll
      for (int dt = 0; dt < 16; ++dt) {
        int drow = dt * 16 + lo;
        short8 bb = *(const short8*)&VB[(drow * 64 + acol) ^ ((drow & 7) << 3)];
        acc[0][dt] = __builtin_amdgcn_mfma_f32_16x16x32_bf16(bb, a0, acc[0][dt], 0, 0, 0);
        acc[1][dt] = __builtin_amdgcn_mfma_f32_16x16x32_bf16(bb, a1, acc[1][dt], 0, 0, 0);
      }
    }
  };

  // pipeline over 64-row subtiles
  int nsc = KC >> 6;
  LOADS(0, 0); STORE(0, 0);
  LOADS(0, 1); STORE(0, 1);
  __syncthreads();
  for (int sc = 0; sc < nsc; ++sc) {
    int nb = (sc + 1) & 1;
    if (sc + 1 < nsc) LOADS(sc + 1, 0);          // in flight during MFMA
    MF(knT[sc & 1], vT[sc & 1]);
    if (sc + 1 < nsc) {
      STORE(nb, 0);
      LOADS(sc + 1, 1);
      STORE(nb, 1);
    }
    __syncthreads();
  }

  // epilogue: bf16 partial [s][b][256 d][256 c] (unchanged, proven)
  size_t base = ((size_t)(s * NB + b)) << 16;
  #pragma unroll
  for (int i = 0; i < 2; i++) {
    int cc = w * 32 + i * 16 + lo;
    #pragma unroll
    for (int dt = 0; dt < 16; ++dt) {
      int dd = dt * 16 + hi * 4;
      #pragma unroll
      for (int r = 0; r < 4; r++)
        partial[base + (size_t)(dd + r) * 256 + cc] = f2bf(acc[i][dt][r]);
    }
  }
}

// ---------------- K2: elementwise reduce partials, scale 1/N, write kvT[d][c] bf16 ----------------
__global__ __launch_bounds__(256) void red_kernel(const u16* __restrict__ partial,
                                                  u16* __restrict__ kvT, int splits) {
  int j = blockIdx.x * 256 + threadIdx.x;   // 0..65535
  int b = j >> 13;
  int e0 = (j & 8191) * 8;
  size_t off = ((size_t)b << 16) + e0;
  const float inv = 1.0f / 4096.0f;
  float sum[8] = {0.f, 0.f, 0.f, 0.f, 0.f, 0.f, 0.f, 0.f};
  for (int s = 0; s < splits; ++s) {
    u16x8 p = *(const u16x8*)&partial[(((size_t)s * NB) << 16) + off];
    #pragma unroll
    for (int x = 0; x < 8; ++x) sum[x] += bf2f(p[x]);
  }
  u16x8 o;
  #pragma unroll
  for (int x = 0; x < 8; ++x) o[x] = f2bf(sum[x] * inv);
  *(u16x8*)&kvT[off] = o;
}

// ---------------- K3: out = normalize(q) @ kv ----------------
// 512 blocks x 512 threads (8 waves). Wave w owns d-tiles {2w,2w+1}; kv frags in regs.
// 4 n-tiles (16 rows) per block, double-buffered LDS + register prefetch, 1 barrier/tile.
__global__ __launch_bounds__(512) void ctx_kernel(const float* __restrict__ query,
                                                  const u16* __restrict__ kvT,
                                                  float* __restrict__ out) {
  __shared__ __align__(16) u16 qn[2][16 * 256];  // 2 x 8 KB q-hat tiles, XOR-swizzled
  int t = threadIdx.x;
  int b = blockIdx.y;
  int tile0 = blockIdx.x * 4;
  int w = t >> 6, lane = t & 63, lo = lane & 15, hi = lane >> 4;
  int row = t >> 5, l32 = t & 31;  // staging role: 16 rows x 32 segs x 8 floats
  const float* qbase = query + (size_t)b * NN * CDIM + (size_t)row * CDIM + l32 * 8;

  // 1) issue tile-0 q loads first (HBM latency hides under the kv prologue)
  const float* qr0 = qbase + (size_t)(tile0 * 16) * CDIM;
  v4f x0 = *(const v4f*)qr0;
  v4f x1 = *(const v4f*)(qr0 + 4);

  // 2) this wave's kv B-fragments (L2-resident, loaded once per block)
  const u16* kvb = kvT + ((size_t)b << 16);
  short8 Bf[2][8];
  #pragma unroll
  for (int i = 0; i < 2; i++) {
    int dr = (2 * w + i) * 16 + lo;
    #pragma unroll
    for (int kc = 0; kc < 8; kc++)
      Bf[i][kc] = *(const short8*)&kvb[(size_t)dr * 256 + kc * 32 + 8 * hi];
  }

  // 3) norm tile 0, stage to LDS[0]
  {
    float ss = x0[0]*x0[0] + x0[1]*x0[1] + x0[2]*x0[2] + x0[3]*x0[3]
             + x1[0]*x1[0] + x1[1]*x1[1] + x1[2]*x1[2] + x1[3]*x1[3];
    #pragma unroll
    for (int m = 1; m < 32; m <<= 1) ss += __shfl_xor(ss, m);
    float sc = 1.0f / fmaxf(sqrtf(ss), 1e-12f);
    u16x8 qb;
    qb[0] = f2bf(x0[0] * sc); qb[1] = f2bf(x0[1] * sc);
    qb[2] = f2bf(x0[2] * sc); qb[3] = f2bf(x0[3] * sc);
    qb[4] = f2bf(x1[0] * sc); qb[5] = f2bf(x1[1] * sc);
    qb[6] = f2bf(x1[2] * sc); qb[7] = f2bf(x1[3] * sc);
    *(u16x8*)&qn[0][(row * 256 + l32 * 8) ^ ((row & 7) << 3)] = qb;
  }

  int cur = 0;
  #pragma unroll
  for (int nt = 0; nt < 4; ++nt) {
    // prefetch next tile's q into registers (flies during MFMA+store below)
    v4f p0, p1;
    if (nt < 3) {
      const float* qr = qbase + (size_t)((tile0 + nt + 1) * 16) * CDIM;
      p0 = *(const v4f*)qr;
      p1 = *(const v4f*)(qr + 4);
    }
    __syncthreads();  // LDS[cur] writes visible to all waves
    // A-frags + MFMA + store for tile nt
    short8 Af[8];
    #pragma unroll
    for (int kc = 0; kc < 8; kc++)
      Af[kc] = *(const short8*)&qn[cur][(lo * 256 + kc * 32 + 8 * hi) ^ ((lo & 7) << 3)];
    v4f acc0 = (v4f){0.f, 0.f, 0.f, 0.f};
    v4f acc1 = (v4f){0.f, 0.f, 0.f, 0.f};
    #pragma unroll
    for (int kc = 0; kc < 8; kc++) {
      acc0 = __builtin_amdgcn_mfma_f32_16x16x32_bf16(Af[kc], Bf[0][kc], acc0, 0, 0, 0);
      acc1 = __builtin_amdgcn_mfma_f32_16x16x32_bf16(Af[kc], Bf[1][kc], acc1, 0, 0, 0);
    }
    int n0 = (tile0 + nt) * 16;
    #pragma unroll
    for (int r = 0; r < 4; r++) {
      size_t ro = (size_t)(b * NN + n0 + 4 * hi + r) * CDIM;
      out[ro + (2 * w) * 16 + lo] = acc0[r];
      out[ro + (2 * w + 1) * 16 + lo] = acc1[r];
    }
    // norm prefetched tile, stage into other buffer
    if (nt < 3) {
      float ss = p0[0]*p0[0] + p0[1]*p0[1] + p0[2]*p0[2] + p0[3]*p0[3]
               + p1[0]*p1[0] + p1[1]*p1[1] + p1[2]*p1[2] + p1[3]*p1[3];
      #pragma unroll
      for (int m = 1; m < 32; m <<= 1) ss += __shfl_xor(ss, m);
      float sc = 1.0f / fmaxf(sqrtf(ss), 1e-12f);
      u16x8 qb;
      qb[0] = f2bf(p0[0] * sc); qb[1] = f2bf(p0[1] * sc);
      qb[2] = f2bf(p0[2] * sc); qb[3] = f2bf(p0[3] * sc);
      qb[4] = f2bf(p1[0] * sc); qb[5] = f2bf(p1[1] * sc);
      qb[6] = f2bf(p1[2] * sc); qb[7] = f2bf(p1[3] * sc);
      *(u16x8*)&qn[cur ^ 1][(row * 256 + l32 * 8) ^ ((row & 7) << 3)] = qb;
      cur ^= 1;
    }
  }
}

extern "C" void kernel_launch(void* const* d_in, const int* in_sizes, int n_in,
                              void* d_out, int out_size, void* d_ws, size_t ws_size,
                              hipStream_t stream) {
  const float* q = (const float*)d_in[0];
  const float* k = (const float*)d_in[1];
  const float* v = (const float*)d_in[2];
  float* out = (float*)d_out;

  // ws layout: [partial: splits*8*256*256 bf16][kvT: 8*256*256 bf16]
  int splits = 32;
  while (splits > 2) {
    size_t need = ((size_t)splits + 1ull) * 1048576ull;
    if (need <= ws_size) break;
    splits >>= 1;
  }
  u16* partial = (u16*)d_ws;
  u16* kvT = (u16*)((char*)d_ws + (size_t)splits * 1048576ull);

  kv_kernel<<<dim3(splits, NB), dim3(512), 0, stream>>>(k, v, partial, MM / splits);
  red_kernel<<<dim3(256), dim3(256), 0, stream>>>(partial, kvT, splits);
  ctx_kernel<<<dim3(64, NB), dim3(512), 0, stream>>>(q, kvT, out);
}